// Round 5
// baseline (387.414 us; speedup 1.0000x reference)
//
#include <hip/hip_runtime.h>

#define EPS 1e-5f
#define ECHUNK 64

typedef _Float16 half8 __attribute__((ext_vector_type(8)));
typedef _Float16 half4v __attribute__((ext_vector_type(4)));
typedef float float4v __attribute__((ext_vector_type(4)));

static __device__ __forceinline__ unsigned pkmax16(unsigned a, unsigned b) {
    unsigned d;
    asm("v_pk_max_f16 %0, %1, %2" : "=v"(d) : "v"(a), "v"(b));
    return d;
}

// ---------------- fused: weight prep + new_bxyz gather + Pmat build ----------------
// Pmat[r] = [pos.yzw f16 | feat[r] f16]  (the per-point MLP input row, padded to 64)
__global__ void prep_gather_kernel(const float* __restrict__ W0, const float* __restrict__ W1,
                                   const float* __restrict__ W2, _Float16* __restrict__ W0t,
                                   _Float16* __restrict__ W1t, _Float16* __restrict__ W2t,
                                   const float4* __restrict__ bxyz, const int* __restrict__ sidx,
                                   float4* __restrict__ out, int M,
                                   const float* __restrict__ feat, _Float16* __restrict__ Pmat,
                                   int N) {
    int i = blockIdx.x * blockDim.x + threadIdx.x;
    if (i < 4096) {                    // W0 [64 k][64 n] -> W0t [n][k]
        int k = i >> 6, n = i & 63;
        W0t[(size_t)n * 64 + k] = (_Float16)W0[i];
    } else if (i < 12288) {            // W1 [64 k][128 n] -> W1t [n][k]
        int j = i - 4096; int k = j >> 7, n = j & 127;
        W1t[(size_t)n * 64 + k] = (_Float16)W1[j];
    } else if (i < 45056) {            // W2 [128 k][256 n] -> W2t [n][k]
        int j = i - 12288; int k = j >> 8, n = j & 255;
        W2t[(size_t)n * 128 + k] = (_Float16)W2[j];
    } else if (i < 45056 + M) {        // out0[j] = bxyz[sidx[j]]
        int j = i - 45056;
        out[j] = bxyz[sidx[j]];
    } else {                           // Pmat build: one half8 per thread
        int j2 = i - (45056 + M);
        if (j2 < N * 8) {
            int r = j2 >> 3, c8 = j2 & 7;
            const float* frow = feat + (size_t)r * 61;
            half8 h;
            if (c8 == 0) {
                float4 P = bxyz[r];
                h[0] = (_Float16)P.y;
                h[1] = (_Float16)P.z;
                h[2] = (_Float16)P.w;
#pragma unroll
                for (int u = 0; u < 5; ++u) h[3 + u] = (_Float16)frow[u];
            } else {
                const float* p = frow + c8 * 8 - 3;
#pragma unroll
                for (int u = 0; u < 8; ++u) h[u] = (_Float16)p[u];
            }
            *(half8*)&Pmat[(size_t)r * 64 + c8 * 8] = h;
        }
    }
}

// ---------------- point (f16 MFMA): GD = Pmat @ W0 + b0 -> fp16 [N,64] ----------------
// 128 rows/block, K=64, 4 waves x (2 mt x 4 nt) 16x16x32 MFMAs.
// Staging is a pure aligned half8 copy (no div, no cvt, b128 LDS writes).
__global__ __launch_bounds__(256, 4) void point_kernel(
    const _Float16* __restrict__ Pmat,
    const _Float16* __restrict__ W0t, const float* __restrict__ b0,
    _Float16* __restrict__ GDh, int N) {
    __shared__ _Float16 As[128 * 72];   // [r][k] pad 72 (2-way bank alias = free)
    int t = threadIdx.x;
    int row0 = blockIdx.x * 128;
#pragma unroll
    for (int j = 0; j < 4; ++j) {
        int i8 = t + j * 256;            // 1024 half8 = 128 r x 8
        int r = i8 >> 3, c8 = i8 & 7;
        int rr = min(row0 + r, N - 1);
        *(half8*)&As[r * 72 + c8 * 8] = *(const half8*)&Pmat[(size_t)rr * 64 + c8 * 8];
    }
    __syncthreads();
    int w = t >> 6, lane = t & 63, quad = lane >> 4, l16 = lane & 15;
    int mwave = w * 32;
    float4v acc[2][4] = {};
#pragma unroll
    for (int kc = 0; kc < 2; ++kc) {
        int koff = kc * 32 + quad * 8;
        half8 af[2], bf[4];
#pragma unroll
        for (int mt = 0; mt < 2; ++mt)
            af[mt] = *(const half8*)&As[(mwave + mt * 16 + l16) * 72 + koff];
#pragma unroll
        for (int nt = 0; nt < 4; ++nt)
            bf[nt] = *(const half8*)&W0t[(size_t)(nt * 16 + l16) * 64 + koff];
#pragma unroll
        for (int mt = 0; mt < 2; ++mt)
#pragma unroll
            for (int nt = 0; nt < 4; ++nt)
                acc[mt][nt] = __builtin_amdgcn_mfma_f32_16x16x32_f16(af[mt], bf[nt], acc[mt][nt], 0, 0, 0);
    }
    float b0v[4];
#pragma unroll
    for (int nt = 0; nt < 4; ++nt) b0v[nt] = b0[nt * 16 + l16];
    __syncthreads();   // all af reads done; reuse As as [r][c] output staging
#pragma unroll
    for (int mt = 0; mt < 2; ++mt)
#pragma unroll
        for (int i = 0; i < 4; ++i) {
            int rloc = mwave + mt * 16 + quad * 4 + i;
#pragma unroll
            for (int nt = 0; nt < 4; ++nt)
                As[rloc * 72 + nt * 16 + l16] = (_Float16)(acc[mt][nt][i] + b0v[nt]);
        }
    __syncthreads();
#pragma unroll
    for (int j = 0; j < 4; ++j) {
        int i8 = t + j * 256;            // 1024 half8 = 128 r x 8
        int r = i8 >> 3, c8 = i8 & 7;
        if (row0 + r < N)
            *(half8*)&GDh[(size_t)(row0 + r) * 64 + c8 * 8] = *(const half8*)&As[r * 72 + c8 * 8];
    }
}

// ---------------- edge pass: packed 2-edges-per-load segmented max (R2 formulation) ----------------
// Identity: max_j(gu_j - S) == (max_j gu_j) - S, so inner loop is pure f16 max; cvt+sub at flush.
// Packing: per pair of edges (2j, 2j+1), lanes 0-31 load a dword (channels 2c0,2c0+1) of the
// even edge's GD row, lanes 32-63 of the odd edge's row -> 256B per wave instruction.
// Row index for each half delivered by one ds_bpermute; accumulate with v_pk_max_f16.
// At flush: __shfl_xor(32) + pk_max merges the two half-wave partial maxes; each lane then
// owns channel ch = 2*(lane&31) + (lane>=32). Branch tests are wave-uniform SGPR bit-tests.
__global__ __launch_bounds__(256, 8) void edge_kernel(
    const float4* __restrict__ nbxyz4,
    const int* __restrict__ e_point, const int* __restrict__ e_new,
    const _Float16* __restrict__ GDh, const float* __restrict__ W0,
    float* __restrict__ agg, int E) {
    int lane = threadIdx.x & 63;
    int gwave = blockIdx.x * 4 + (threadIdx.x >> 6);
    int base = __builtin_amdgcn_readfirstlane(gwave * ECHUNK);
    if (base >= E) return;
    int n = min(ECHUNK, E - base);

    if (n == ECHUNK) {
        bool hi = lane >= 32;
        int c0 = lane & 31;
        int ch = c0 * 2 + (hi ? 1 : 0);
        float wx = W0[ch], wy = W0[64 + ch], wz = W0[128 + ch];
        const unsigned NEGP = 0xFBFFFBFFu;   // packed {-65504h, -65504h}

        int ep = e_point[base + lane];
        int en = e_new[base + lane];

        // boundary bitmask: bit e set iff edge e starts a new segment within this chunk
        int prev = __shfl_up(en, 1);
        unsigned long long bm = __ballot(lane == 0 || en != prev);
        unsigned blo = __builtin_amdgcn_readfirstlane((unsigned)bm);
        unsigned bhi = __builtin_amdgcn_readfirstlane((unsigned)(bm >> 32));
        unsigned long long bmask = (((unsigned long long)bhi << 32) | blo) & ~1ull;

        int curseg = __builtin_amdgcn_readlane(en, 0);
        unsigned amax = NEGP;
        int laneoff = c0 * 4;            // dword byte-offset within the 128B row
        int permbase = hi ? 4 : 0;       // bpermute byte addr: lane reads ep of edge 2j+hi

#define FLUSH_SEG()  do {                                                          \
        unsigned other_ = (unsigned)__shfl_xor((int)amax, 32);                     \
        unsigned comb_ = pkmax16(amax, other_);                                    \
        unsigned bits_ = hi ? (comb_ >> 16) : (comb_ & 0xffffu);                   \
        _Float16 hm_ = __builtin_bit_cast(_Float16, (unsigned short)bits_);        \
        float4 Q_ = nbxyz4[curseg];                                                \
        float S_ = fmaf(Q_.y, wx, fmaf(Q_.z, wy, Q_.w * wz));                      \
        float v_ = fmaxf(0.f, (float)hm_ - S_);                                    \
        atomicMax((int*)&agg[(size_t)curseg * 64 + ch], __float_as_int(v_));       \
    } while (0)

        // two groups of 16 pairs: 16 dword loads (4KB/wave) in flight per group
#pragma unroll
        for (int grp = 0; grp < 2; ++grp) {
            unsigned gu[16];
#pragma unroll
            for (int j = 0; j < 16; ++j) {
                int p = __builtin_amdgcn_ds_bpermute(permbase + (grp * 16 + j) * 8, ep);
                unsigned off = ((unsigned)p << 7) + laneoff;
                gu[j] = *(const unsigned*)((const char*)GDh + off);
            }
#pragma unroll
            for (int j = 0; j < 16; ++j) {
                int e0 = (grp * 16 + j) * 2;
                if ((bmask >> e0) & 1) {                 // boundary at even edge
                    FLUSH_SEG();
                    curseg = __builtin_amdgcn_readlane(en, e0);
                    amax = NEGP;
                }
                if ((bmask >> (e0 + 1)) & 1) {           // boundary between the pair
                    amax = pkmax16(amax, hi ? NEGP : gu[j]);   // even edge -> old segment
                    FLUSH_SEG();
                    curseg = __builtin_amdgcn_readlane(en, e0 + 1);
                    amax = hi ? gu[j] : NEGP;                  // odd edge -> new segment
                } else {
                    amax = pkmax16(amax, gu[j]);
                }
            }
        }
        FLUSH_SEG();
#undef FLUSH_SEG
    } else {
        // partial tail chunk (not hit for E % 64 == 0): simple exact scalar path, channel = lane
        float wx = W0[lane], wy = W0[64 + lane], wz = W0[128 + lane];
        int idx = min(base + lane, E - 1);
        int ep = e_point[idx];
        int en = e_new[idx];
        int curseg = -1;
        float runmax = 0.f, S = 0.f;
        for (int e = 0; e < n; ++e) {
            int p = __builtin_amdgcn_readlane(ep, e);
            int s = __builtin_amdgcn_readlane(en, e);
            if (s != curseg) {
                if (curseg >= 0)
                    atomicMax((int*)&agg[(size_t)curseg * 64 + lane], __float_as_int(runmax));
                curseg = s;
                runmax = 0.f;
                float4 Q = nbxyz4[s];
                S = fmaf(Q.y, wx, fmaf(Q.z, wy, Q.w * wz));
            }
            float h = (float)GDh[(size_t)p * 64 + lane] - S;
            runmax = fmaxf(runmax, h);
        }
        if (curseg >= 0)
            atomicMax((int*)&agg[(size_t)curseg * 64 + lane], __float_as_int(runmax));
    }
}

// ---------------- GEMM1 (f16 MFMA): y1h = agg @ W1 -> f16 [M,128] + moment partials ----------------
// 128 rows/block, K=64, 4 waves x (2 mt x 8 nt).
__global__ __launch_bounds__(256, 2) void gemm1_kernel(
    const float* __restrict__ agg, const _Float16* __restrict__ W1t,
    _Float16* __restrict__ y1h, float* __restrict__ p1sum, float* __restrict__ p1sq, int M) {
    __shared__ _Float16 As[128 * 72];     // [r][k], then reused as [r][c-half] output staging
    __shared__ float red[4096];           // 128 cols x 16 slots, sum + sq
    int t = threadIdx.x;
    int row0 = blockIdx.x * 128;
#pragma unroll
    for (int j = 0; j < 8; ++j) {
        int i4 = t + j * 256;              // 2048 float4 = 128 r x 16
        int r = i4 >> 4, k4 = i4 & 15;
        float4 v = make_float4(0.f, 0.f, 0.f, 0.f);
        if (row0 + r < M) v = ((const float4*)agg)[(size_t)(row0 + r) * 16 + k4];
        half4v h;
        h[0] = (_Float16)v.x; h[1] = (_Float16)v.y; h[2] = (_Float16)v.z; h[3] = (_Float16)v.w;
        *(half4v*)&As[r * 72 + k4 * 4] = h;
    }
    __syncthreads();
    int w = t >> 6, lane = t & 63, quad = lane >> 4, l16 = lane & 15;
    int mwave = w * 32;
    float4v acc[2][8] = {};
#pragma unroll
    for (int kc = 0; kc < 2; ++kc) {
        int koff = kc * 32 + quad * 8;
        half8 af[2], bf[8];
#pragma unroll
        for (int mt = 0; mt < 2; ++mt)
            af[mt] = *(const half8*)&As[(mwave + mt * 16 + l16) * 72 + koff];
#pragma unroll
        for (int nt = 0; nt < 8; ++nt)
            bf[nt] = *(const half8*)&W1t[(size_t)(nt * 16 + l16) * 64 + koff];
#pragma unroll
        for (int mt = 0; mt < 2; ++mt)
#pragma unroll
            for (int nt = 0; nt < 8; ++nt)
                acc[mt][nt] = __builtin_amdgcn_mfma_f32_16x16x32_f16(af[mt], bf[nt], acc[mt][nt], 0, 0, 0);
    }
    // per-col moment partials (padded rows contribute exact 0)
    float s[8] = {}, q[8] = {};
#pragma unroll
    for (int mt = 0; mt < 2; ++mt)
#pragma unroll
        for (int i = 0; i < 4; ++i)
#pragma unroll
            for (int nt = 0; nt < 8; ++nt) {
                float a = acc[mt][nt][i];
                s[nt] += a; q[nt] += a * a;
            }
    int slot = w * 4 + quad;
#pragma unroll
    for (int nt = 0; nt < 8; ++nt) {
        int c = nt * 16 + l16;
        red[c * 16 + slot] = s[nt];
        red[2048 + c * 16 + slot] = q[nt];
    }
    __syncthreads();   // red complete; As frag reads complete
    if (t < 128) {
        float ss = 0.f, qq = 0.f;
#pragma unroll
        for (int i = 0; i < 16; ++i) { ss += red[t * 16 + i]; qq += red[2048 + t * 16 + i]; }
        p1sum[(size_t)blockIdx.x * 128 + t] = ss;
        p1sq[(size_t)blockIdx.x * 128 + t] = qq;
    }
    // y1 writeout via LDS transpose, two 64-col passes
#pragma unroll
    for (int half = 0; half < 2; ++half) {
#pragma unroll
        for (int mt = 0; mt < 2; ++mt)
#pragma unroll
            for (int i = 0; i < 4; ++i) {
                int rloc = mwave + mt * 16 + quad * 4 + i;
#pragma unroll
                for (int nt = 0; nt < 4; ++nt)
                    As[rloc * 72 + nt * 16 + l16] = (_Float16)acc[mt][half * 4 + nt][i];
            }
        __syncthreads();
#pragma unroll
        for (int j = 0; j < 4; ++j) {
            int i8 = t + j * 256;          // 1024 half8 = 128 r x 8
            int r = i8 >> 3, c8 = i8 & 7;
            if (row0 + r < M)
                *(half8*)&y1h[(size_t)(row0 + r) * 128 + half * 64 + c8 * 8] =
                    *(const half8*)&As[r * 72 + c8 * 8];
        }
        __syncthreads();
    }
}

// ---------------- reduce moment partials -> per-channel BN scale/shift ----------------
__global__ void stats_kernel(const float* __restrict__ psum, const float* __restrict__ psq,
                             const float* __restrict__ g, const float* __restrict__ beta,
                             float* __restrict__ scale, float* __restrict__ shift,
                             int nblk, int ncols, float invM) {
    __shared__ float ss[256], qq[256];
    int c = blockIdx.x;
    int t = threadIdx.x;
    float s = 0.f, q = 0.f;
    for (int b = t; b < nblk; b += 256) {
        s += psum[(size_t)b * ncols + c];
        q += psq[(size_t)b * ncols + c];
    }
    ss[t] = s; qq[t] = q;
    __syncthreads();
    for (int off = 128; off > 0; off >>= 1) {
        if (t < off) { ss[t] += ss[t + off]; qq[t] += qq[t + off]; }
        __syncthreads();
    }
    if (t == 0) {
        float mean = ss[0] * invM;
        float var = qq[0] * invM - mean * mean;
        float sc = g[c] * rsqrtf(var + EPS);
        scale[c] = sc;
        shift[c] = beta[c] - mean * sc;
    }
}

// ---------------- GEMM2 (f16 MFMA): y2h = bnrelu1(y1h) @ W2 -> f16 [M,256] + moment partials ----
// block = 128M x 128N, 4 waves each 64M x 64N, K=128 fully staged in LDS.
// y2 stored f16 via LDS transpose (coalesced half8); BN2 stats computed from exact f32 accums.
__global__ __launch_bounds__(256, 2) void gemm2_kernel(
    const _Float16* __restrict__ y1h, const _Float16* __restrict__ W2t,
    const float* __restrict__ scale1, const float* __restrict__ shift1,
    _Float16* __restrict__ y2h, float* __restrict__ p2sum, float* __restrict__ p2sq,
    int M, int nbn) {
    __shared__ _Float16 As[128 * 136];   // [m][k] pad 8 halves; reused as output staging
    __shared__ _Float16 Bs[128 * 136];   // [n][k] pad 8 halves; reused as moment red
    int t = threadIdx.x;
    int bm = blockIdx.x / nbn;
    int bn = blockIdx.x % nbn;
    int row0 = bm * 128;
    // stage A: bnrelu1(y1h) -> f16
#pragma unroll
    for (int j = 0; j < 8; ++j) {
        int i8 = t + j * 256;              // 2048 half8 = 128 r x 16
        int r = i8 >> 4, k8 = i8 & 15;
        half8 hv = {};
        if (row0 + r < M) {
            half8 y = *(const half8*)&y1h[(size_t)(row0 + r) * 128 + k8 * 8];
            float4 sca = ((const float4*)scale1)[k8 * 2];
            float4 scb = ((const float4*)scale1)[k8 * 2 + 1];
            float4 sha = ((const float4*)shift1)[k8 * 2];
            float4 shb = ((const float4*)shift1)[k8 * 2 + 1];
            float sc[8] = {sca.x, sca.y, sca.z, sca.w, scb.x, scb.y, scb.z, scb.w};
            float sh[8] = {sha.x, sha.y, sha.z, sha.w, shb.x, shb.y, shb.z, shb.w};
#pragma unroll
            for (int u = 0; u < 8; ++u)
                hv[u] = (_Float16)fmaxf(0.f, fmaf((float)y[u], sc[u], sh[u]));
        }
        *(half8*)&As[r * 136 + k8 * 8] = hv;
    }
    // stage B: W2t rows n0..n0+127
    int n0 = bn * 128;
#pragma unroll
    for (int j = 0; j < 8; ++j) {
        int i8 = t + j * 256;              // 2048 half8 = 128 n x 16
        int nn = i8 >> 4, k8 = i8 & 15;
        *(half8*)&Bs[nn * 136 + k8 * 8] = *(const half8*)&W2t[(size_t)(n0 + nn) * 128 + k8 * 8];
    }
    __syncthreads();
    int w = t >> 6, lane = t & 63;
    int quad = lane >> 4, l16 = lane & 15;
    int mwave = (w >> 1) * 64, nwave = (w & 1) * 64;
    float4v acc[4][4] = {};   // [mt][nt]
#pragma unroll
    for (int kc = 0; kc < 4; ++kc) {
        int koff = kc * 32 + quad * 8;
        half8 af[4], bf[4];
#pragma unroll
        for (int mt = 0; mt < 4; ++mt)
            af[mt] = *(const half8*)&As[(mwave + mt * 16 + l16) * 136 + koff];
#pragma unroll
        for (int nt = 0; nt < 4; ++nt)
            bf[nt] = *(const half8*)&Bs[(nwave + nt * 16 + l16) * 136 + koff];
#pragma unroll
        for (int mt = 0; mt < 4; ++mt)
#pragma unroll
            for (int nt = 0; nt < 4; ++nt)
                acc[mt][nt] = __builtin_amdgcn_mfma_f32_16x16x32_f16(af[mt], bf[nt], acc[mt][nt], 0, 0, 0);
    }
    // per-lane column partials from exact f32 accumulators
    float s[4] = {}, q[4] = {};
#pragma unroll
    for (int mt = 0; mt < 4; ++mt)
#pragma unroll
        for (int i = 0; i < 4; ++i)
#pragma unroll
            for (int nt = 0; nt < 4; ++nt) {
                float a = acc[mt][nt][i];
                s[nt] += a; q[nt] += a * a;
            }
    __syncthreads();   // all fragment reads of As/Bs complete
    float* red = (float*)Bs;   // [128 cols][8 slots] sum, sq at +1024
    int slot = (w >> 1) * 4 + quad;
#pragma unroll
    for (int nt = 0; nt < 4; ++nt) {
        int c = (w & 1) * 64 + nt * 16 + l16;
        red[c * 8 + slot] = s[nt];
        red[1024 + c * 8 + slot] = q[nt];
    }
    // stage y2 f16 into As [128 r][128 c] stride 136
#pragma unroll
    for (int mt = 0; mt < 4; ++mt)
#pragma unroll
        for (int i = 0; i < 4; ++i) {
            int rloc = mwave + mt * 16 + quad * 4 + i;
#pragma unroll
            for (int nt = 0; nt < 4; ++nt)
                As[rloc * 136 + nwave + nt * 16 + l16] = (_Float16)acc[mt][nt][i];
        }
    __syncthreads();
    if (t < 128) {
        float ss = 0.f, qq = 0.f;
#pragma unroll
        for (int i = 0; i < 8; ++i) { ss += red[t * 8 + i]; qq += red[1024 + t * 8 + i]; }
        p2sum[(size_t)bm * 256 + n0 + t] = ss;
        p2sq[(size_t)bm * 256 + n0 + t] = qq;
    }
    // coalesced y2h writeout: 2048 half8 = 128 r x 16
#pragma unroll
    for (int j = 0; j < 8; ++j) {
        int i8 = t + j * 256;
        int r = i8 >> 4, c8 = i8 & 15;
        if (row0 + r < M)
            *(half8*)&y2h[(size_t)(row0 + r) * 256 + n0 + c8 * 8] =
                *(const half8*)&As[r * 136 + c8 * 8];
    }
}

// ---------------- BN2+ReLU: out1 = relu(y2h * sc + sh), f16 in / f32 out ----------------
__global__ void apply2_kernel(const _Float16* __restrict__ y2h, float4* __restrict__ x,
                              const float* __restrict__ scale2, const float* __restrict__ shift2,
                              int n8) {
    int i = blockIdx.x * blockDim.x + threadIdx.x;   // one half8 -> 8 output floats
    if (i >= n8) return;
    int c8 = i & 31;                                  // 32 half8 per 256-col row
    half8 y = *(const half8*)&y2h[(size_t)i * 8];
    float4 sc0 = ((const float4*)scale2)[c8 * 2];
    float4 sc1 = ((const float4*)scale2)[c8 * 2 + 1];
    float4 sh0 = ((const float4*)shift2)[c8 * 2];
    float4 sh1 = ((const float4*)shift2)[c8 * 2 + 1];
    float4 a, b;
    a.x = fmaxf(0.f, fmaf((float)y[0], sc0.x, sh0.x));
    a.y = fmaxf(0.f, fmaf((float)y[1], sc0.y, sh0.y));
    a.z = fmaxf(0.f, fmaf((float)y[2], sc0.z, sh0.z));
    a.w = fmaxf(0.f, fmaf((float)y[3], sc0.w, sh0.w));
    b.x = fmaxf(0.f, fmaf((float)y[4], sc1.x, sh1.x));
    b.y = fmaxf(0.f, fmaf((float)y[5], sc1.y, sh1.y));
    b.z = fmaxf(0.f, fmaf((float)y[6], sc1.z, sh1.z));
    b.w = fmaxf(0.f, fmaf((float)y[7], sc1.w, sh1.w));
    x[(size_t)i * 2] = a;
    x[(size_t)i * 2 + 1] = b;
}

extern "C" void kernel_launch(void* const* d_in, const int* in_sizes, int n_in,
                              void* d_out, int out_size, void* d_ws, size_t ws_size,
                              hipStream_t stream) {
    const float* bxyz  = (const float*)d_in[0];
    const float* feat  = (const float*)d_in[1];
    const int*   sidx  = (const int*)d_in[2];
    const int*   e_point = (const int*)d_in[3];
    const int*   e_new = (const int*)d_in[4];
    const float* W0    = (const float*)d_in[5];
    const float* b0    = (const float*)d_in[6];
    const float* W1    = (const float*)d_in[7];
    const float* g1    = (const float*)d_in[9];
    const float* beta1 = (const float*)d_in[10];
    const float* W2    = (const float*)d_in[11];
    const float* g2    = (const float*)d_in[13];
    const float* beta2 = (const float*)d_in[14];
    int N = in_sizes[0] / 4;     // 400000
    int M = in_sizes[2];         // 100000
    int E = in_sizes[3];         // 3200000

    float* out0 = (float*)d_out;                       // new_bxyz [M,4]
    float* out1 = (float*)d_out + (size_t)M * 4;       // x [M,256]

    float* ws = (float*)d_ws;
    size_t o = 0;
    float* agg = ws + o; o += (size_t)M * 64;
    _Float16* y1h = (_Float16*)(ws + o); o += (size_t)M * 64;   // f16 [M,128]
    _Float16* GDh = (_Float16*)(ws + o); o += (size_t)N * 32;   // f16 [N,64]; dead after edge
    _Float16* W0t = (_Float16*)(ws + o); o += 2048;
    _Float16* W1t = (_Float16*)(ws + o); o += 4096;
    _Float16* W2t = (_Float16*)(ws + o); o += 16384;
    int nblk1 = (M + 127) / 128;
    int nblk2m = (M + 127) / 128;
    int nbn = 2;
    float* p1sum = ws + o; o += (size_t)nblk1 * 128;
    float* p1sq  = ws + o; o += (size_t)nblk1 * 128;
    float* p2sum = ws + o; o += (size_t)nblk2m * 256;
    float* p2sq  = ws + o; o += (size_t)nblk2m * 256;
    float* scale1 = ws + o; o += 128;
    float* shift1 = ws + o; o += 128;
    float* scale2 = ws + o; o += 256;
    float* shift2 = ws + o; o += 256;
    // Pmat [N,64] f16 = 51.2 MB aliases agg+y1h (25.6+25.6 MB), both dead until after point_kernel
    _Float16* Pmat = (_Float16*)ws;
    // y2h [M,256] f16 = 51.2 MB aliases GDh [N,64] f16 (51.2 MB), dead after edge_kernel
    _Float16* y2h = GDh;

    int total_t = 45056 + M + N * 8;
    prep_gather_kernel<<<(total_t + 255) / 256, 256, 0, stream>>>(
        W0, W1, W2, W0t, W1t, W2t, (const float4*)bxyz, sidx, (float4*)out0, M,
        feat, Pmat, N);
    point_kernel<<<(N + 127) / 128, 256, 0, stream>>>(Pmat, W0t, b0, GDh, N);
    hipMemsetAsync(agg, 0, (size_t)M * 64 * sizeof(float), stream);   // after point: agg aliases Pmat
    int nwaves = (E + ECHUNK - 1) / ECHUNK;
    edge_kernel<<<(nwaves + 3) / 4, 256, 0, stream>>>((const float4*)out0, e_point, e_new,
                                                      GDh, W0, agg, E);
    gemm1_kernel<<<nblk1, 256, 0, stream>>>(agg, W1t, y1h, p1sum, p1sq, M);
    stats_kernel<<<128, 256, 0, stream>>>(p1sum, p1sq, g1, beta1, scale1, shift1, nblk1, 128, 1.f / M);
    gemm2_kernel<<<nblk2m * nbn, 256, 0, stream>>>(y1h, W2t, scale1, shift1, y2h, p2sum, p2sq, M, nbn);
    stats_kernel<<<256, 256, 0, stream>>>(p2sum, p2sq, g2, beta2, scale2, shift2, nblk2m, 256, 1.f / M);
    apply2_kernel<<<((M * 32) + 255) / 256, 256, 0, stream>>>(y2h, (float4*)out1, scale2, shift2, M * 32);
}

// Round 6
// 383.793 us; speedup vs baseline: 1.0094x; 1.0094x over previous
//
#include <hip/hip_runtime.h>

#define EPS 1e-5f
#define ECHUNK 64

typedef _Float16 half8 __attribute__((ext_vector_type(8)));
typedef _Float16 half4v __attribute__((ext_vector_type(4)));
typedef float float4v __attribute__((ext_vector_type(4)));

static __device__ __forceinline__ unsigned pkmax16(unsigned a, unsigned b) {
    unsigned d;
    asm("v_pk_max_f16 %0, %1, %2" : "=v"(d) : "v"(a), "v"(b));
    return d;
}

// ---------------- fused: weight prep + new_bxyz gather + agg zero-init ----------------
__global__ void prep_gather_kernel(const float* __restrict__ W0, const float* __restrict__ W1,
                                   const float* __restrict__ W2, _Float16* __restrict__ W0t,
                                   _Float16* __restrict__ W1t, _Float16* __restrict__ W2t,
                                   const float4* __restrict__ bxyz, const int* __restrict__ sidx,
                                   float4* __restrict__ out, int M, float4* __restrict__ agg4) {
    int i = blockIdx.x * blockDim.x + threadIdx.x;
    if (i < 4096) {                    // W0 [64 k][64 n] -> W0t [n][k]
        int k = i >> 6, n = i & 63;
        W0t[(size_t)n * 64 + k] = (_Float16)W0[i];
    } else if (i < 12288) {            // W1 [64 k][128 n] -> W1t [n][k]
        int j = i - 4096; int k = j >> 7, n = j & 127;
        W1t[(size_t)n * 64 + k] = (_Float16)W1[j];
    } else if (i < 45056) {            // W2 [128 k][256 n] -> W2t [n][k]
        int j = i - 12288; int k = j >> 8, n = j & 255;
        W2t[(size_t)n * 128 + k] = (_Float16)W2[j];
    } else if (i < 45056 + M) {        // out0[j] = bxyz[sidx[j]]
        int j = i - 45056;
        out[j] = bxyz[sidx[j]];
    } else {                           // agg = 0  (M*64 floats = M*16 float4)
        int j = i - (45056 + M);
        if (j < M * 16) agg4[j] = make_float4(0.f, 0.f, 0.f, 0.f);
    }
}

// ---------------- point (f16 MFMA): GD = [P.yzw ; feat] @ W0 + b0 -> fp16 [N,64] ----------------
// 128 rows/block, K=64 (3 pos + 61 feat), 4 waves x (2 mt x 4 nt) 16x16x32 MFMAs.
__global__ __launch_bounds__(256, 4) void point_kernel(
    const float* __restrict__ feat, const float4* __restrict__ bxyz4,
    const _Float16* __restrict__ W0t, const float* __restrict__ b0,
    _Float16* __restrict__ GDh, int N) {
    __shared__ _Float16 As[128 * 72];   // [r][k] pad 72 (2-way bank alias = free)
    int t = threadIdx.x;
    int row0 = blockIdx.x * 128;
    if (t < 128) {
        int r = min(row0 + t, N - 1);
        float4 P = bxyz4[r];
        As[t * 72 + 0] = (_Float16)P.y;
        As[t * 72 + 1] = (_Float16)P.z;
        As[t * 72 + 2] = (_Float16)P.w;
    }
    // feat tile is flat-contiguous and float4-aligned: row0*61 % 4 == 0 (row0 mult of 128)
    const float* fbase = feat + (size_t)row0 * 61;
    int avail = (int)min((size_t)7808, (size_t)(N - row0) * 61);
#pragma unroll
    for (int j = 0; j < 8; ++j) {
        int base = (t + j * 256) * 4;
        if (base < avail) {
            float4 v = *(const float4*)&fbase[base];
            float fv[4] = {v.x, v.y, v.z, v.w};
#pragma unroll
            for (int u = 0; u < 4; ++u) {
                int flat = base + u;
                int r = flat / 61;
                int k = flat - r * 61;
                As[r * 72 + 3 + k] = (_Float16)fv[u];
            }
        }
    }
    __syncthreads();
    int w = t >> 6, lane = t & 63, quad = lane >> 4, l16 = lane & 15;
    int mwave = w * 32;
    float4v acc[2][4] = {};
#pragma unroll
    for (int kc = 0; kc < 2; ++kc) {
        int koff = kc * 32 + quad * 8;
        half8 af[2], bf[4];
#pragma unroll
        for (int mt = 0; mt < 2; ++mt)
            af[mt] = *(const half8*)&As[(mwave + mt * 16 + l16) * 72 + koff];
#pragma unroll
        for (int nt = 0; nt < 4; ++nt)
            bf[nt] = *(const half8*)&W0t[(size_t)(nt * 16 + l16) * 64 + koff];
#pragma unroll
        for (int mt = 0; mt < 2; ++mt)
#pragma unroll
            for (int nt = 0; nt < 4; ++nt)
                acc[mt][nt] = __builtin_amdgcn_mfma_f32_16x16x32_f16(af[mt], bf[nt], acc[mt][nt], 0, 0, 0);
    }
    float b0v[4];
#pragma unroll
    for (int nt = 0; nt < 4; ++nt) b0v[nt] = b0[nt * 16 + l16];
    __syncthreads();   // all af reads done; reuse As as [r][c] output staging
#pragma unroll
    for (int mt = 0; mt < 2; ++mt)
#pragma unroll
        for (int i = 0; i < 4; ++i) {
            int rloc = mwave + mt * 16 + quad * 4 + i;
#pragma unroll
            for (int nt = 0; nt < 4; ++nt)
                As[rloc * 72 + nt * 16 + l16] = (_Float16)(acc[mt][nt][i] + b0v[nt]);
        }
    __syncthreads();
#pragma unroll
    for (int j = 0; j < 4; ++j) {
        int i8 = t + j * 256;            // 1024 half8 = 128 r x 8
        int r = i8 >> 3, c8 = i8 & 7;
        if (row0 + r < N)
            *(half8*)&GDh[(size_t)(row0 + r) * 64 + c8 * 8] = *(const half8*)&As[r * 72 + c8 * 8];
    }
}

// ---------------- edge pass: packed 2-edges-per-load segmented max (R2 formulation) ----------------
__global__ __launch_bounds__(256, 8) void edge_kernel(
    const float4* __restrict__ nbxyz4,
    const int* __restrict__ e_point, const int* __restrict__ e_new,
    const _Float16* __restrict__ GDh, const float* __restrict__ W0,
    float* __restrict__ agg, int E) {
    int lane = threadIdx.x & 63;
    int gwave = blockIdx.x * 4 + (threadIdx.x >> 6);
    int base = __builtin_amdgcn_readfirstlane(gwave * ECHUNK);
    if (base >= E) return;
    int n = min(ECHUNK, E - base);

    if (n == ECHUNK) {
        bool hi = lane >= 32;
        int c0 = lane & 31;
        int ch = c0 * 2 + (hi ? 1 : 0);
        float wx = W0[ch], wy = W0[64 + ch], wz = W0[128 + ch];
        const unsigned NEGP = 0xFBFFFBFFu;   // packed {-65504h, -65504h}

        int ep = e_point[base + lane];
        int en = e_new[base + lane];

        int prev = __shfl_up(en, 1);
        unsigned long long bm = __ballot(lane == 0 || en != prev);
        unsigned blo = __builtin_amdgcn_readfirstlane((unsigned)bm);
        unsigned bhi = __builtin_amdgcn_readfirstlane((unsigned)(bm >> 32));
        unsigned long long bmask = (((unsigned long long)bhi << 32) | blo) & ~1ull;

        int curseg = __builtin_amdgcn_readlane(en, 0);
        unsigned amax = NEGP;
        int laneoff = c0 * 4;
        int permbase = hi ? 4 : 0;

#define FLUSH_SEG()  do {                                                          \
        unsigned other_ = (unsigned)__shfl_xor((int)amax, 32);                     \
        unsigned comb_ = pkmax16(amax, other_);                                    \
        unsigned bits_ = hi ? (comb_ >> 16) : (comb_ & 0xffffu);                   \
        _Float16 hm_ = __builtin_bit_cast(_Float16, (unsigned short)bits_);        \
        float4 Q_ = nbxyz4[curseg];                                                \
        float S_ = fmaf(Q_.y, wx, fmaf(Q_.z, wy, Q_.w * wz));                      \
        float v_ = fmaxf(0.f, (float)hm_ - S_);                                    \
        atomicMax((int*)&agg[(size_t)curseg * 64 + ch], __float_as_int(v_));       \
    } while (0)

#pragma unroll
        for (int grp = 0; grp < 2; ++grp) {
            unsigned gu[16];
#pragma unroll
            for (int j = 0; j < 16; ++j) {
                int p = __builtin_amdgcn_ds_bpermute(permbase + (grp * 16 + j) * 8, ep);
                unsigned off = ((unsigned)p << 7) + laneoff;
                gu[j] = *(const unsigned*)((const char*)GDh + off);
            }
#pragma unroll
            for (int j = 0; j < 16; ++j) {
                int e0 = (grp * 16 + j) * 2;
                if ((bmask >> e0) & 1) {
                    FLUSH_SEG();
                    curseg = __builtin_amdgcn_readlane(en, e0);
                    amax = NEGP;
                }
                if ((bmask >> (e0 + 1)) & 1) {
                    amax = pkmax16(amax, hi ? NEGP : gu[j]);
                    FLUSH_SEG();
                    curseg = __builtin_amdgcn_readlane(en, e0 + 1);
                    amax = hi ? gu[j] : NEGP;
                } else {
                    amax = pkmax16(amax, gu[j]);
                }
            }
        }
        FLUSH_SEG();
#undef FLUSH_SEG
    } else {
        float wx = W0[lane], wy = W0[64 + lane], wz = W0[128 + lane];
        int idx = min(base + lane, E - 1);
        int ep = e_point[idx];
        int en = e_new[idx];
        int curseg = -1;
        float runmax = 0.f, S = 0.f;
        for (int e = 0; e < n; ++e) {
            int p = __builtin_amdgcn_readlane(ep, e);
            int s = __builtin_amdgcn_readlane(en, e);
            if (s != curseg) {
                if (curseg >= 0)
                    atomicMax((int*)&agg[(size_t)curseg * 64 + lane], __float_as_int(runmax));
                curseg = s;
                runmax = 0.f;
                float4 Q = nbxyz4[s];
                S = fmaf(Q.y, wx, fmaf(Q.z, wy, Q.w * wz));
            }
            float h = (float)GDh[(size_t)p * 64 + lane] - S;
            runmax = fmaxf(runmax, h);
        }
        if (curseg >= 0)
            atomicMax((int*)&agg[(size_t)curseg * 64 + lane], __float_as_int(runmax));
    }
}

// ---------------- GEMM1 (f16 MFMA): y1h = agg @ W1 -> f16 [M,128] + moment partials ----------------
__global__ __launch_bounds__(256, 2) void gemm1_kernel(
    const float* __restrict__ agg, const _Float16* __restrict__ W1t,
    _Float16* __restrict__ y1h, float* __restrict__ p1sum, float* __restrict__ p1sq, int M) {
    __shared__ _Float16 As[128 * 72];     // [r][k], then reused as [r][c-half] output staging
    __shared__ float red[4096];           // 128 cols x 16 slots, sum + sq
    int t = threadIdx.x;
    int row0 = blockIdx.x * 128;
#pragma unroll
    for (int j = 0; j < 8; ++j) {
        int i4 = t + j * 256;              // 2048 float4 = 128 r x 16
        int r = i4 >> 4, k4 = i4 & 15;
        float4 v = make_float4(0.f, 0.f, 0.f, 0.f);
        if (row0 + r < M) v = ((const float4*)agg)[(size_t)(row0 + r) * 16 + k4];
        half4v h;
        h[0] = (_Float16)v.x; h[1] = (_Float16)v.y; h[2] = (_Float16)v.z; h[3] = (_Float16)v.w;
        *(half4v*)&As[r * 72 + k4 * 4] = h;
    }
    __syncthreads();
    int w = t >> 6, lane = t & 63, quad = lane >> 4, l16 = lane & 15;
    int mwave = w * 32;
    float4v acc[2][8] = {};
#pragma unroll
    for (int kc = 0; kc < 2; ++kc) {
        int koff = kc * 32 + quad * 8;
        half8 af[2], bf[8];
#pragma unroll
        for (int mt = 0; mt < 2; ++mt)
            af[mt] = *(const half8*)&As[(mwave + mt * 16 + l16) * 72 + koff];
#pragma unroll
        for (int nt = 0; nt < 8; ++nt)
            bf[nt] = *(const half8*)&W1t[(size_t)(nt * 16 + l16) * 64 + koff];
#pragma unroll
        for (int mt = 0; mt < 2; ++mt)
#pragma unroll
            for (int nt = 0; nt < 8; ++nt)
                acc[mt][nt] = __builtin_amdgcn_mfma_f32_16x16x32_f16(af[mt], bf[nt], acc[mt][nt], 0, 0, 0);
    }
    float s[8] = {}, q[8] = {};
#pragma unroll
    for (int mt = 0; mt < 2; ++mt)
#pragma unroll
        for (int i = 0; i < 4; ++i)
#pragma unroll
            for (int nt = 0; nt < 8; ++nt) {
                float a = acc[mt][nt][i];
                s[nt] += a; q[nt] += a * a;
            }
    int slot = w * 4 + quad;
#pragma unroll
    for (int nt = 0; nt < 8; ++nt) {
        int c = nt * 16 + l16;
        red[c * 16 + slot] = s[nt];
        red[2048 + c * 16 + slot] = q[nt];
    }
    __syncthreads();
    if (t < 128) {
        float ss = 0.f, qq = 0.f;
#pragma unroll
        for (int i = 0; i < 16; ++i) { ss += red[t * 16 + i]; qq += red[2048 + t * 16 + i]; }
        p1sum[(size_t)blockIdx.x * 128 + t] = ss;
        p1sq[(size_t)blockIdx.x * 128 + t] = qq;
    }
#pragma unroll
    for (int half = 0; half < 2; ++half) {
#pragma unroll
        for (int mt = 0; mt < 2; ++mt)
#pragma unroll
            for (int i = 0; i < 4; ++i) {
                int rloc = mwave + mt * 16 + quad * 4 + i;
#pragma unroll
                for (int nt = 0; nt < 4; ++nt)
                    As[rloc * 72 + nt * 16 + l16] = (_Float16)acc[mt][half * 4 + nt][i];
            }
        __syncthreads();
#pragma unroll
        for (int j = 0; j < 4; ++j) {
            int i8 = t + j * 256;
            int r = i8 >> 3, c8 = i8 & 7;
            if (row0 + r < M)
                *(half8*)&y1h[(size_t)(row0 + r) * 128 + half * 64 + c8 * 8] =
                    *(const half8*)&As[r * 72 + c8 * 8];
        }
        __syncthreads();
    }
}

// ---------------- reduce moment partials -> per-channel BN scale/shift ----------------
__global__ void stats_kernel(const float* __restrict__ psum, const float* __restrict__ psq,
                             const float* __restrict__ g, const float* __restrict__ beta,
                             float* __restrict__ scale, float* __restrict__ shift,
                             int nblk, int ncols, float invM) {
    __shared__ float ss[256], qq[256];
    int c = blockIdx.x;
    int t = threadIdx.x;
    float s = 0.f, q = 0.f;
    for (int b = t; b < nblk; b += 256) {
        s += psum[(size_t)b * ncols + c];
        q += psq[(size_t)b * ncols + c];
    }
    ss[t] = s; qq[t] = q;
    __syncthreads();
    for (int off = 128; off > 0; off >>= 1) {
        if (t < off) { ss[t] += ss[t + off]; qq[t] += qq[t + off]; }
        __syncthreads();
    }
    if (t == 0) {
        float mean = ss[0] * invM;
        float var = qq[0] * invM - mean * mean;
        float sc = g[c] * rsqrtf(var + EPS);
        scale[c] = sc;
        shift[c] = beta[c] - mean * sc;
    }
}

// ---------------- GEMM2-stats (f16 MFMA): moment partials of bnrelu1(y1h) @ W2, no y2 output ----
// block = 128M x 128N, 4 waves each 64M x 64N, K=128 fully staged in LDS.
__global__ __launch_bounds__(256, 2) void gemm2s_kernel(
    const _Float16* __restrict__ y1h, const _Float16* __restrict__ W2t,
    const float* __restrict__ scale1, const float* __restrict__ shift1,
    float* __restrict__ p2sum, float* __restrict__ p2sq, int M, int nbn) {
    __shared__ _Float16 As[128 * 136];
    __shared__ _Float16 Bs[128 * 136];
    int t = threadIdx.x;
    int bm = blockIdx.x / nbn;
    int bn = blockIdx.x % nbn;
    int row0 = bm * 128;
#pragma unroll
    for (int j = 0; j < 8; ++j) {
        int i8 = t + j * 256;
        int r = i8 >> 4, k8 = i8 & 15;
        half8 hv = {};
        if (row0 + r < M) {
            half8 y = *(const half8*)&y1h[(size_t)(row0 + r) * 128 + k8 * 8];
            float4 sca = ((const float4*)scale1)[k8 * 2];
            float4 scb = ((const float4*)scale1)[k8 * 2 + 1];
            float4 sha = ((const float4*)shift1)[k8 * 2];
            float4 shb = ((const float4*)shift1)[k8 * 2 + 1];
            float sc[8] = {sca.x, sca.y, sca.z, sca.w, scb.x, scb.y, scb.z, scb.w};
            float sh[8] = {sha.x, sha.y, sha.z, sha.w, shb.x, shb.y, shb.z, shb.w};
#pragma unroll
            for (int u = 0; u < 8; ++u)
                hv[u] = (_Float16)fmaxf(0.f, fmaf((float)y[u], sc[u], sh[u]));
        }
        *(half8*)&As[r * 136 + k8 * 8] = hv;
    }
    int n0 = bn * 128;
#pragma unroll
    for (int j = 0; j < 8; ++j) {
        int i8 = t + j * 256;
        int nn = i8 >> 4, k8 = i8 & 15;
        *(half8*)&Bs[nn * 136 + k8 * 8] = *(const half8*)&W2t[(size_t)(n0 + nn) * 128 + k8 * 8];
    }
    __syncthreads();
    int w = t >> 6, lane = t & 63;
    int quad = lane >> 4, l16 = lane & 15;
    int mwave = (w >> 1) * 64, nwave = (w & 1) * 64;
    float4v acc[4][4] = {};
#pragma unroll
    for (int kc = 0; kc < 4; ++kc) {
        int koff = kc * 32 + quad * 8;
        half8 af[4], bf[4];
#pragma unroll
        for (int mt = 0; mt < 4; ++mt)
            af[mt] = *(const half8*)&As[(mwave + mt * 16 + l16) * 136 + koff];
#pragma unroll
        for (int nt = 0; nt < 4; ++nt)
            bf[nt] = *(const half8*)&Bs[(nwave + nt * 16 + l16) * 136 + koff];
#pragma unroll
        for (int mt = 0; mt < 4; ++mt)
#pragma unroll
            for (int nt = 0; nt < 4; ++nt)
                acc[mt][nt] = __builtin_amdgcn_mfma_f32_16x16x32_f16(af[mt], bf[nt], acc[mt][nt], 0, 0, 0);
    }
    float s[4] = {}, q[4] = {};
#pragma unroll
    for (int mt = 0; mt < 4; ++mt)
#pragma unroll
        for (int i = 0; i < 4; ++i)
#pragma unroll
            for (int nt = 0; nt < 4; ++nt) {
                float a = acc[mt][nt][i];
                s[nt] += a; q[nt] += a * a;
            }
    __syncthreads();
    float* red = (float*)Bs;   // [128 cols][8 slots] sum, sq at +1024
    int slot = (w >> 1) * 4 + quad;
#pragma unroll
    for (int nt = 0; nt < 4; ++nt) {
        int c = (w & 1) * 64 + nt * 16 + l16;
        red[c * 8 + slot] = s[nt];
        red[1024 + c * 8 + slot] = q[nt];
    }
    __syncthreads();
    if (t < 128) {
        float ss = 0.f, qq = 0.f;
#pragma unroll
        for (int i = 0; i < 8; ++i) { ss += red[t * 8 + i]; qq += red[1024 + t * 8 + i]; }
        p2sum[(size_t)bm * 256 + n0 + t] = ss;
        p2sq[(size_t)bm * 256 + n0 + t] = qq;
    }
}

// ---------------- GEMM2-apply: recompute identical accums, BN2+ReLU, write out1 f32 ----------------
// Same staging + MFMA sequence as gemm2s (deterministic => bit-identical accums).
// Output coalesced via 2 x 64-col LDS transpose passes (f32 [128][68] overlays As exactly).
__global__ __launch_bounds__(256, 2) void gemm2a_kernel(
    const _Float16* __restrict__ y1h, const _Float16* __restrict__ W2t,
    const float* __restrict__ scale1, const float* __restrict__ shift1,
    const float* __restrict__ scale2, const float* __restrict__ shift2,
    float* __restrict__ out1, int M, int nbn) {
    __shared__ _Float16 As[128 * 136];   // staging, then f32 [128][68] output transpose
    __shared__ _Float16 Bs[128 * 136];
    int t = threadIdx.x;
    int bm = blockIdx.x / nbn;
    int bn = blockIdx.x % nbn;
    int row0 = bm * 128;
#pragma unroll
    for (int j = 0; j < 8; ++j) {
        int i8 = t + j * 256;
        int r = i8 >> 4, k8 = i8 & 15;
        half8 hv = {};
        if (row0 + r < M) {
            half8 y = *(const half8*)&y1h[(size_t)(row0 + r) * 128 + k8 * 8];
            float4 sca = ((const float4*)scale1)[k8 * 2];
            float4 scb = ((const float4*)scale1)[k8 * 2 + 1];
            float4 sha = ((const float4*)shift1)[k8 * 2];
            float4 shb = ((const float4*)shift1)[k8 * 2 + 1];
            float sc[8] = {sca.x, sca.y, sca.z, sca.w, scb.x, scb.y, scb.z, scb.w};
            float sh[8] = {sha.x, sha.y, sha.z, sha.w, shb.x, shb.y, shb.z, shb.w};
#pragma unroll
            for (int u = 0; u < 8; ++u)
                hv[u] = (_Float16)fmaxf(0.f, fmaf((float)y[u], sc[u], sh[u]));
        }
        *(half8*)&As[r * 136 + k8 * 8] = hv;
    }
    int n0 = bn * 128;
#pragma unroll
    for (int j = 0; j < 8; ++j) {
        int i8 = t + j * 256;
        int nn = i8 >> 4, k8 = i8 & 15;
        *(half8*)&Bs[nn * 136 + k8 * 8] = *(const half8*)&W2t[(size_t)(n0 + nn) * 128 + k8 * 8];
    }
    __syncthreads();
    int w = t >> 6, lane = t & 63;
    int quad = lane >> 4, l16 = lane & 15;
    int mwave = (w >> 1) * 64, nwave = (w & 1) * 64;
    float4v acc[4][4] = {};
#pragma unroll
    for (int kc = 0; kc < 4; ++kc) {
        int koff = kc * 32 + quad * 8;
        half8 af[4], bf[4];
#pragma unroll
        for (int mt = 0; mt < 4; ++mt)
            af[mt] = *(const half8*)&As[(mwave + mt * 16 + l16) * 136 + koff];
#pragma unroll
        for (int nt = 0; nt < 4; ++nt)
            bf[nt] = *(const half8*)&Bs[(nwave + nt * 16 + l16) * 136 + koff];
#pragma unroll
        for (int mt = 0; mt < 4; ++mt)
#pragma unroll
            for (int nt = 0; nt < 4; ++nt)
                acc[mt][nt] = __builtin_amdgcn_mfma_f32_16x16x32_f16(af[mt], bf[nt], acc[mt][nt], 0, 0, 0);
    }
    // BN2 + ReLU on exact f32 accums
    float sc2[4], sh2[4];
#pragma unroll
    for (int nt = 0; nt < 4; ++nt) {
        int c = n0 + nwave + nt * 16 + l16;
        sc2[nt] = scale2[c];
        sh2[nt] = shift2[c];
    }
    __syncthreads();   // all As/Bs fragment reads complete
    float* As32 = (float*)As;   // [128 r][68 c] f32 = 34816 B, exactly As
#pragma unroll
    for (int half = 0; half < 2; ++half) {
        if ((w & 1) == half) {   // waves holding this 64-col half stage it
#pragma unroll
            for (int mt = 0; mt < 4; ++mt)
#pragma unroll
                for (int i = 0; i < 4; ++i) {
                    int rloc = mwave + mt * 16 + quad * 4 + i;
#pragma unroll
                    for (int nt = 0; nt < 4; ++nt)
                        As32[rloc * 68 + nt * 16 + l16] =
                            fmaxf(0.f, fmaf(acc[mt][nt][i], sc2[nt], sh2[nt]));
                }
        }
        __syncthreads();
#pragma unroll
        for (int j = 0; j < 8; ++j) {
            int i4 = t + j * 256;          // 2048 float4 = 128 r x 16
            int r = i4 >> 4, c4 = i4 & 15;
            if (row0 + r < M)
                *(float4*)&out1[(size_t)(row0 + r) * 256 + n0 + half * 64 + c4 * 4] =
                    *(const float4*)&As32[r * 68 + c4 * 4];
        }
        __syncthreads();
    }
}

extern "C" void kernel_launch(void* const* d_in, const int* in_sizes, int n_in,
                              void* d_out, int out_size, void* d_ws, size_t ws_size,
                              hipStream_t stream) {
    const float* bxyz  = (const float*)d_in[0];
    const float* feat  = (const float*)d_in[1];
    const int*   sidx  = (const int*)d_in[2];
    const int*   e_point = (const int*)d_in[3];
    const int*   e_new = (const int*)d_in[4];
    const float* W0    = (const float*)d_in[5];
    const float* b0    = (const float*)d_in[6];
    const float* W1    = (const float*)d_in[7];
    const float* g1    = (const float*)d_in[9];
    const float* beta1 = (const float*)d_in[10];
    const float* W2    = (const float*)d_in[11];
    const float* g2    = (const float*)d_in[13];
    const float* beta2 = (const float*)d_in[14];
    int N = in_sizes[0] / 4;     // 400000
    int M = in_sizes[2];         // 100000
    int E = in_sizes[3];         // 3200000

    float* out0 = (float*)d_out;                       // new_bxyz [M,4]
    float* out1 = (float*)d_out + (size_t)M * 4;       // x [M,256]

    float* ws = (float*)d_ws;
    size_t o = 0;
    float* agg = ws + o; o += (size_t)M * 64;
    _Float16* y1h = (_Float16*)(ws + o); o += (size_t)M * 64;   // f16 [M,128]
    _Float16* GDh = (_Float16*)(ws + o); o += (size_t)N * 32;   // f16 [N,64]
    _Float16* W0t = (_Float16*)(ws + o); o += 2048;
    _Float16* W1t = (_Float16*)(ws + o); o += 4096;
    _Float16* W2t = (_Float16*)(ws + o); o += 16384;
    int nblk1 = (M + 127) / 128;
    int nblk2m = (M + 127) / 128;
    int nbn = 2;
    float* p1sum = ws + o; o += (size_t)nblk1 * 128;
    float* p1sq  = ws + o; o += (size_t)nblk1 * 128;
    float* p2sum = ws + o; o += (size_t)nblk2m * 256;
    float* p2sq  = ws + o; o += (size_t)nblk2m * 256;
    float* scale1 = ws + o; o += 128;
    float* shift1 = ws + o; o += 128;
    float* scale2 = ws + o; o += 256;
    float* shift2 = ws + o; o += 256;

    int total_t = 45056 + M + M * 16;
    prep_gather_kernel<<<(total_t + 255) / 256, 256, 0, stream>>>(
        W0, W1, W2, W0t, W1t, W2t, (const float4*)bxyz, sidx, (float4*)out0, M, (float4*)agg);
    point_kernel<<<(N + 127) / 128, 256, 0, stream>>>(feat, (const float4*)bxyz, W0t, b0, GDh, N);
    int nwaves = (E + ECHUNK - 1) / ECHUNK;
    edge_kernel<<<(nwaves + 3) / 4, 256, 0, stream>>>((const float4*)out0, e_point, e_new,
                                                      GDh, W0, agg, E);
    gemm1_kernel<<<nblk1, 256, 0, stream>>>(agg, W1t, y1h, p1sum, p1sq, M);
    stats_kernel<<<128, 256, 0, stream>>>(p1sum, p1sq, g1, beta1, scale1, shift1, nblk1, 128, 1.f / M);
    gemm2s_kernel<<<nblk2m * nbn, 256, 0, stream>>>(y1h, W2t, scale1, shift1, p2sum, p2sq, M, nbn);
    stats_kernel<<<256, 256, 0, stream>>>(p2sum, p2sq, g2, beta2, scale2, shift2, nblk2m, 256, 1.f / M);
    gemm2a_kernel<<<nblk2m * nbn, 256, 0, stream>>>(y1h, W2t, scale1, shift1, scale2, shift2,
                                                    out1, M, nbn);
}